// Round 15
// baseline (125.283 us; speedup 1.0000x reference)
//
#include <hip/hip_runtime.h>
#include <cstddef>

#define K 64
#define D 768
#define D4 192   // D/4

__device__ __forceinline__ float d4f(float4 a, float4 b) {
  return a.x*b.x + a.y*b.y + a.z*b.z + a.w*b.w;
}
__device__ __forceinline__ float4 a4(float4 a, float4 b) {
  return make_float4(a.x+b.x, a.y+b.y, a.z+b.z, a.w+b.w);
}
__device__ __forceinline__ unsigned short f2bf(float x) {
  unsigned int u = __float_as_uint(x);
  unsigned int r = (u + 0x7FFFu + ((u >> 16) & 1u)) >> 16;
  return (unsigned short)r;
}
__device__ __forceinline__ float bflo(unsigned u) { return __uint_as_float(u << 16); }
__device__ __forceinline__ float bfhi(unsigned u) { return __uint_as_float(u & 0xFFFF0000u); }

typedef __attribute__((ext_vector_type(8)))  short bf16x8;
typedef __attribute__((ext_vector_type(16))) float f32x16;

// =====================================================================
// FAST PATH (N=32768, NC=256, C=128)
// =====================================================================
#define NCF 256
#define CF  128
#define NF  32768

// ---- K2v11: fused cast + per-chunk sums GEMM; 64-col slabs, 4 blocks/CU ----
#define LDT3 68   // Vt row stride (bf16 elems) for 64-col slab
#define LDM  136  // Mt row stride
__global__ __launch_bounds__(256) void k2_v11(
    const float* __restrict__ inputs, const int* __restrict__ labels,
    const float* __restrict__ cavg, unsigned short* __restrict__ cavgb,
    float* __restrict__ cn2,
    unsigned short* __restrict__ sums, int* __restrict__ cnts_t)
{
  __shared__ unsigned short Vt[128 * LDT3];   // 17408 B (reused as So)
  __shared__ unsigned short Mt[64 * LDM];     // 17408 B
  __shared__ int hist[64];
  const int bi = blockIdx.x;
  const int tid = threadIdx.x;

  if (bi >= NCF * 12) {   // ---- cavg tail: cast + exact row norms ----
    int wave = (bi - NCF * 12) * 4 + (tid >> 6);
    int l = tid & 63;
    if (wave >= K) return;
    const float* src = cavg + (size_t)wave * D;
    unsigned short* dst = cavgb + (size_t)wave * D;
    float sq = 0.f;
#pragma unroll
    for (int t = 0; t < 3; ++t) {
      float4 v = ((const float4*)src)[t * 64 + l];
      sq += v.x*v.x + v.y*v.y + v.z*v.z + v.w*v.w;
      ushort4 o; o.x = f2bf(v.x); o.y = f2bf(v.y); o.z = f2bf(v.z); o.w = f2bf(v.w);
      ((ushort4*)dst)[t * 64 + l] = o;
    }
#pragma unroll
    for (int mm = 1; mm <= 32; mm <<= 1) sq += __shfl_xor(sq, mm);
    if (l == 0) cn2[wave] = sq;
    return;
  }

  const int m = bi / 12, g = bi % 12;
  const int w = tid >> 6, l = tid & 63;
  const int r31 = l & 31, kh = l >> 5;
  const int ch = w & 1;    // class-half (rows of output)
  const int cw = w >> 1;   // col-half (32-col tile within 64-col slab)

  // issue f32 slab loads first; latency hides under Mt build
  float4 fr[8];
#pragma unroll
  for (int it = 0; it < 8; ++it) {
    int flat = it * 256 + tid;
    int row = flat >> 4, c4 = flat & 15;
    fr[it] = *(const float4*)(inputs + (size_t)(m * 128 + row) * D + g * 64 + c4 * 4);
  }

  for (int e = tid; e < 64 * LDM / 2; e += 256) ((unsigned int*)Mt)[e] = 0u;
  if (tid < 64) hist[tid] = 0;
  __syncthreads();
  if (tid < 128) {
    int lab = labels[m * 128 + tid];
    Mt[lab * LDM + tid] = 0x3F80;   // 1.0 bf16
    if (g == 0) atomicAdd(&hist[lab], 1);
  }
  __syncthreads();
  if (g == 0 && tid < 64) cnts_t[tid * NCF + m] = hist[tid];

  // convert + write Vt (LDS only)
#pragma unroll
  for (int it = 0; it < 8; ++it) {
    int flat = it * 256 + tid;
    int row = flat >> 4, c4 = flat & 15;
    ushort4 o;
    o.x = f2bf(fr[it].x); o.y = f2bf(fr[it].y);
    o.z = f2bf(fr[it].z); o.w = f2bf(fr[it].w);
    *(ushort4*)(Vt + row * LDT3 + c4 * 4) = o;
  }
  __syncthreads();

  f32x16 acc = (f32x16){};
#pragma unroll
  for (int kk = 0; kk < 8; ++kk) {
    bf16x8 a = *(const bf16x8*)(Mt + (ch * 32 + r31) * LDM + kk * 16 + kh * 8);
    bf16x8 b;
#pragma unroll
    for (int r = 0; r < 8; ++r)
      b[r] = *(const short*)(Vt + (kk * 16 + kh * 8 + r) * LDT3 + cw * 32 + r31);
    acc = __builtin_amdgcn_mfma_f32_32x32x16_bf16(a, b, acc, 0, 0, 0);
  }

  // coalesced output: acc -> LDS (reuse Vt) -> row-contiguous global stores
  __syncthreads();
  unsigned short* So = Vt;   // [64][64]
#pragma unroll
  for (int q = 0; q < 16; ++q) {
    int kc = (q & 3) + 8 * (q >> 2) + 4 * kh;
    So[(ch * 32 + kc) * 64 + cw * 32 + r31] = f2bf(acc[q]);
  }
  __syncthreads();
  unsigned short* sp = sums + (size_t)m * (K * D) + g * 64;
#pragma unroll
  for (int it = 0; it < 2; ++it) {
    int flat = it * 256 + tid;
    int row = flat >> 3, c = flat & 7;
    *(uint4*)(sp + (size_t)row * D + c * 8) = *(const uint4*)(So + row * 64 + c * 8);
  }
}

// ---- K3a: level-1 exclusive scan over 16 chunks, IN PLACE on bf16 sums ----
__global__ __launch_bounds__(256) void k3a_scan_lo(
    unsigned short* __restrict__ sums, float* __restrict__ aux)
{
  const int g  = blockIdx.x / 96;
  const int cp = (blockIdx.x % 96) * 256 + threadIdx.x;  // column pair
  const int col = cp * 2;
  float run0 = 0.f, run1 = 0.f;
  for (int m = g * 16; m < g * 16 + 16; ++m) {
    size_t idx = (size_t)m * (K * D) + col;
    unsigned u = *(const unsigned*)(sums + idx);
    float t0 = bflo(u), t1 = bfhi(u);
    *(unsigned*)(sums + idx) = (unsigned)f2bf(run0) | ((unsigned)f2bf(run1) << 16);
    run0 += t0; run1 += t1;
  }
  aux[(size_t)g * (K * D) + col]     = run0;
  aux[(size_t)g * (K * D) + col + 1] = run1;
}

// ---- K3b+: scan group totals (f32); block 192 scans cnts ----
__global__ __launch_bounds__(256) void k3b_plus(
    float* __restrict__ aux, int* __restrict__ cnts_t)
{
  if (blockIdx.x == 192) {
    if (threadIdx.x < K) {
      int k = threadIdx.x;
      int run = 0;
      int* p = cnts_t + k * NCF;
      for (int mm = 0; mm < NCF; ++mm) { int t = p[mm]; p[mm] = run; run += t; }
    }
    return;
  }
  int col = blockIdx.x * 256 + threadIdx.x;
  float run = 0.f;
  for (int g = 0; g < 16; ++g) {
    size_t idx = (size_t)g * (K * D) + col;
    float t = aux[idx]; aux[idx] = run; run += t;
  }
}

// ---- K4a: fused GEMMs, grid 512 (2 blocks/chunk, 2 blocks/CU). Block (m,h)
//      computes output rows 64h..64h+63; writes dotb/pvb/bn2b to global. ----
#define LDV2 136  // bf16 row stride for 128-col tiles
#define LDS2 136
__global__ __launch_bounds__(512, 4) void k4a_gemm(
    const float* __restrict__ inputs, const unsigned short* __restrict__ base,
    const float* __restrict__ aux, const unsigned short* __restrict__ cavgb,
    const int* __restrict__ labels,
    float* __restrict__ dotb, float* __restrict__ pvb, float* __restrict__ bn2b)
{
  __shared__ unsigned short smem[2 * 128 * LDV2];   // Vt|Bt single buffer, 69632 B
  __shared__ float bn2L[64];
  __shared__ int   labL[128];
  unsigned short* Vt = smem;
  unsigned short* Bt = smem + 128 * LDV2;
  const int bi = blockIdx.x;
  const int m = bi >> 1, h = bi & 1;
  const int g = m >> 4;
  const int tid = threadIdx.x;
  const int w = tid >> 6, l = tid & 63;
  const int r31 = l & 31, kh = l >> 5;
  const int wrg = 2 * h + (w & 1);   // global output row-tile 0..3
  const int wc  = w >> 1;            // col-tile 0..3

  if (tid < 128) labL[tid] = labels[m * 128 + tid];
  if (tid < 64) bn2L[tid] = 0.f;

  f32x16 accP = (f32x16){}, accS = (f32x16){};

  float4 vregf[8];
  uint4 breg[2], creg[2];
  float4 areg[4];

#define PREF(sx) do {                                                          \
    _Pragma("unroll")                                                          \
    for (int it = 0; it < 8; ++it) {                                           \
      int flat = it * 512 + tid;                                               \
      int row = flat >> 5, c4 = flat & 31;                                     \
      vregf[it] = *(const float4*)(inputs + (size_t)(m * 128 + row) * D + (sx) * 128 + c4 * 4); \
    }                                                                          \
    _Pragma("unroll")                                                          \
    for (int it = 0; it < 2; ++it) {                                           \
      int flat = it * 512 + tid;                                               \
      int row = flat >> 4, c = flat & 15;                                      \
      breg[it] = *(const uint4*)(base + ((size_t)m * K + row) * D + (sx) * 128 + c * 8); \
      const float* ap = aux + ((size_t)g * K + row) * D + (sx) * 128 + c * 8;  \
      areg[it * 2]     = *(const float4*)ap;                                   \
      areg[it * 2 + 1] = *(const float4*)(ap + 4);                             \
      creg[it] = *(const uint4*)(cavgb + (size_t)row * D + (sx) * 128 + c * 8);\
    }                                                                          \
  } while (0)

#define WRITEB() do {                                                          \
    _Pragma("unroll")                                                          \
    for (int it = 0; it < 8; ++it) {                                           \
      int flat = it * 512 + tid;                                               \
      int row = flat >> 5, c4 = flat & 31;                                     \
      ushort4 o;                                                               \
      o.x = f2bf(vregf[it].x); o.y = f2bf(vregf[it].y);                        \
      o.z = f2bf(vregf[it].z); o.w = f2bf(vregf[it].w);                        \
      *(ushort4*)(Vt + row * LDV2 + c4 * 4) = o;                               \
    }                                                                          \
    _Pragma("unroll")                                                          \
    for (int it = 0; it < 2; ++it) {                                           \
      int flat = it * 512 + tid;                                               \
      int row = flat >> 4, c = flat & 15;                                      \
      uint4 ub = breg[it];                                                     \
      float4 af0 = areg[it * 2], af1 = areg[it * 2 + 1];                       \
      float f0 = bflo(ub.x) + af0.x, f1 = bfhi(ub.x) + af0.y;                  \
      float f2 = bflo(ub.y) + af0.z, f3 = bfhi(ub.y) + af0.w;                  \
      float f4 = bflo(ub.z) + af1.x, f5 = bfhi(ub.z) + af1.y;                  \
      float f6 = bflo(ub.w) + af1.z, f7 = bfhi(ub.w) + af1.w;                  \
      float sq = f0*f0 + f1*f1 + f2*f2 + f3*f3 + f4*f4 + f5*f5 + f6*f6 + f7*f7;\
      sq += __shfl_xor(sq, 1); sq += __shfl_xor(sq, 2);                        \
      sq += __shfl_xor(sq, 4); sq += __shfl_xor(sq, 8);                        \
      if ((l & 15) == 0) atomicAdd(&bn2L[row], sq);                            \
      uint4 u;                                                                 \
      u.x = (unsigned)f2bf(f0) | ((unsigned)f2bf(f1) << 16);                   \
      u.y = (unsigned)f2bf(f2) | ((unsigned)f2bf(f3) << 16);                   \
      u.z = (unsigned)f2bf(f4) | ((unsigned)f2bf(f5) << 16);                   \
      u.w = (unsigned)f2bf(f6) | ((unsigned)f2bf(f7) << 16);                   \
      *(uint4*)(Bt + row * LDV2 + c * 8) = u;                                  \
      *(uint4*)(Bt + (64 + row) * LDV2 + c * 8) = creg[it];                    \
    }                                                                          \
  } while (0)

  PREF(0);

  for (int s = 0; s < 6; ++s) {
    __syncthreads();               // prior MFMA reads of Vt/Bt done
    WRITEB();
    if (s < 5) PREF(s + 1);        // loads land under next MFMA phase
    __syncthreads();               // tile ready
#pragma unroll
    for (int kk = 0; kk < 8; ++kk) {
      bf16x8 av = *(const bf16x8*)(Vt + (32 * wrg + r31) * LDV2 + kk * 16 + kh * 8);
      bf16x8 bB = *(const bf16x8*)(Bt + (32 * wc + r31) * LDV2 + kk * 16 + kh * 8);
      accP = __builtin_amdgcn_mfma_f32_32x32x16_bf16(av, bB, accP, 0, 0, 0);
      if (wc <= wrg) {   // strict-lower + diag tiles only
        bf16x8 bV = *(const bf16x8*)(Vt + (32 * wc + r31) * LDV2 + kk * 16 + kh * 8);
        accS = __builtin_amdgcn_mfma_f32_32x32x16_bf16(av, bV, accS, 0, 0, 0);
      }
    }
  }
#undef PREF
#undef WRITEB

  // ---- pv from Gram diagonal (tiles with wc==wrg) ----
  if (wc == wrg && ((r31 >> 2) & 1) == kh) {
    int q = (r31 & 3) + 4 * (r31 >> 3);
    pvb[(size_t)m * 128 + 32 * wrg + r31] = accS[q];
  }
  __syncthreads();   // bn2L atomics complete
  if (h == 0 && tid < 64) bn2b[m * 64 + tid] = bn2L[tid];

  // ---- masked S (this block's 64 rows) -> SL; one-hot Mt ----
  unsigned short* SL  = smem;                 // [64][LDS2]
  unsigned short* MtL = smem + 64 * LDS2;     // [64][LDS2]
  __syncthreads();   // everyone past LDS reads (MFMA loop done)
#pragma unroll
  for (int q = 0; q < 16; ++q) {
    int i_loc = 32 * (w & 1) + (q & 3) + 8 * (q >> 2) + 4 * kh;
    int i_glob = 64 * h + i_loc;
    int j = 32 * wc + r31;
    SL[i_loc * LDS2 + j] = (j < i_glob) ? f2bf(accS[q]) : (unsigned short)0;
  }
  {
    int j = tid & 127;
    int lab = labL[j];
    int kb = (tid >> 7) * 16;
#pragma unroll
    for (int kk = 0; kk < 16; ++kk) {
      int k = kb + kk;
      MtL[k * LDS2 + j] = (lab == k) ? (unsigned short)0x3F80 : (unsigned short)0;
    }
  }
  __syncthreads();

  // ---- corr = tril_strict(S rows) @ onehot; waves 0-3 (class-col tiles) ----
  if (w < 4) {
#pragma unroll
    for (int kk = 0; kk < 8; ++kk) {
      bf16x8 aS = *(const bf16x8*)(SL + (32 * (w & 1) + r31) * LDS2 + kk * 16 + kh * 8);
      bf16x8 bM = *(const bf16x8*)(MtL + (32 * (w >> 1) + r31) * LDS2 + kk * 16 + kh * 8);
      accP = __builtin_amdgcn_mfma_f32_32x32x16_bf16(aS, bM, accP, 0, 0, 0);
    }
  }

  // ---- dot write to global (register-only per wave; no barrier needed) ----
#pragma unroll
  for (int q = 0; q < 16; ++q) {
    int i_glob = 32 * wrg + (q & 3) + 8 * (q >> 2) + 4 * kh;
    int col = 32 * wc + r31;
    dotb[((size_t)m * 128 + i_glob) * 128 + col] = accP[q];
  }
}

// ---- K5: parallel segment-scan epilogue from global dotb ----
__global__ __launch_bounds__(1024) void k5_ep(
    const float* __restrict__ dotb, const float* __restrict__ pvb,
    const float* __restrict__ bn2b, const int* __restrict__ labels,
    const int* __restrict__ cnts_t, const float* __restrict__ cn2,
    float* __restrict__ out)
{
  __shared__ float pvL[128];
  __shared__ float bn2L[64];
  __shared__ int   labL[128];
  __shared__ float segA[16][64];
  __shared__ float segF[16][64];
  __shared__ float segP[16][64];
  __shared__ int   segH[16][64];
  const int m = blockIdx.x;
  const int tid = threadIdx.x;
  const int w = tid >> 6, l = tid & 63;

  if (tid < 128) { labL[tid] = labels[m * 128 + tid]; pvL[tid] = pvb[(size_t)m * 128 + tid]; }
  if (tid < 64) bn2L[tid] = bn2b[m * 64 + tid];
  __syncthreads();

  const float* dm = dotb + (size_t)m * 128 * 128;

  // segment summaries: wave w owns rows [8w, 8w+8), lane = class
  {
    int k = l;
    float A = 0.f, Fv = 0.f, Pv = 0.f;
    int has = 0;
    int jb = w * 8;
    for (int j = jb; j < jb + 8; ++j) {
      if (labL[j] == k) {
        float t = 2.f * dm[(size_t)j * 128 + k] + pvL[j];
        A += t;
        if (!has) { Fv = t; Pv = pvL[j]; has = 1; }
      }
    }
    segA[w][k] = A; segF[w][k] = Fv; segP[w][k] = Pv; segH[w][k] = has;
  }
  __syncthreads();

  // fold prior segments, then emit 8-row segment
  {
    int k = l;
    bool seen = cnts_t[k * NCF + m] > 0;
    float n = seen ? bn2L[k] : 0.f;
    for (int ww = 0; ww < w; ++ww) {
      if (segH[ww][k]) {
        n = seen ? (n + segA[ww][k])
                 : (segP[ww][k] + segA[ww][k] - segF[ww][k]);
        seen = true;
      }
    }
    float cnk = cn2[k];
    int jb = w * 8;
    for (int j = jb; j < jb + 8; ++j) {
      float dS = dm[(size_t)j * 128 + k];
      float dC = dm[(size_t)j * 128 + 64 + k];
      float pvj = pvL[j];
      int lab = labL[j];
      float val = seen ? dS : dC;
      float nn  = seen ? n : cnk;
      out[(size_t)(m * 128 + j) * K + k] = val * rsqrtf(fmaxf(nn * pvj, 1e-30f));
      if (lab == k) {
        n = seen ? (n + 2.f * dS + pvj) : pvj;
        seen = true;
      }
    }
  }
}

// =====================================================================
// FALLBACK PATH — round-1 pipeline, verbatim (known-correct)
// =====================================================================
__global__ __launch_bounds__(256) void ph1_chunk_sums(
    const float* __restrict__ inputs, const int* __restrict__ labels,
    float* __restrict__ sums, int* __restrict__ cnts, int NC, int C)
{
  __shared__ float acc[4 * K * 64];
  __shared__ int   hist[4 * K];
  const int bi    = blockIdx.x;
  const int chunk = bi / 12, slice = bi % 12;
  const int w = threadIdx.x >> 6, l = threadIdx.x & 63;

  for (int e = threadIdx.x; e < 4 * K * 64; e += 256) acc[e] = 0.f;
  hist[threadIdx.x] = 0;
  __syncthreads();

  const int C4 = C >> 2;
  const long long rbase = (long long)chunk * C + (long long)w * C4;
  float* accw = acc + w * (K * 64);
  for (int j = 0; j < C4; ++j) {
    long long r = rbase + j;
    int lab = labels[r];
    float v = inputs[r * D + slice * 64 + l];
    accw[lab * 64 + l] += v;
    if (slice == 0 && l == 0) hist[w * K + lab]++;
  }
  __syncthreads();

  float* sp = sums + (long long)chunk * (K * D) + slice * 64;
  for (int e = threadIdx.x; e < K * 64; e += 256) {
    int k = e >> 6, dl = e & 63;
    float s = acc[0*K*64 + e] + acc[1*K*64 + e] + acc[2*K*64 + e] + acc[3*K*64 + e];
    sp[k * D + dl] = s;
  }
  if (slice == 0 && threadIdx.x < K) {
    cnts[chunk * K + threadIdx.x] =
        hist[0*K + threadIdx.x] + hist[1*K + threadIdx.x] +
        hist[2*K + threadIdx.x] + hist[3*K + threadIdx.x];
  }
}

__global__ __launch_bounds__(256) void ph2a_scan_sums(float* __restrict__ sums, int NC)
{
  const int tid = blockIdx.x * 256 + threadIdx.x;
  float run = 0.f;
  for (int m = 0; m < NC; ++m) {
    long long idx = (long long)m * (K * D) + tid;
    float t = sums[idx];
    sums[idx] = run;
    run += t;
  }
}

__global__ void ph2b_scan_cnts(int* __restrict__ cnts, int NC)
{
  const int k = threadIdx.x;
  int run = 0;
  for (int m = 0; m < NC; ++m) {
    int t = cnts[m * K + k];
    cnts[m * K + k] = run;
    run += t;
  }
}

__global__ __launch_bounds__(256, 4) void ph3_scan(
    const float* __restrict__ inputs, const int* __restrict__ labels,
    const float* __restrict__ cavg, const float* __restrict__ base,
    const int* __restrict__ cnts, float* __restrict__ out, int NC, int C)
{
  const int bi = blockIdx.x;
  int chunk, quad;
  if (NC >= 8) {
    int xcd = bi & 7, slot = bi >> 3;
    chunk = xcd * (NC >> 3) + (slot >> 2);
    quad  = slot & 3;
  } else {
    chunk = bi >> 2; quad = bi & 3;
  }
  const int w = threadIdx.x >> 6, l = threadIdx.x & 63;
  const int k0 = (quad * 4 + w) * 4;

  const int cb = chunk * K + k0;
  bool vg0 = (cnts[cb+0] == 0), vg1 = (cnts[cb+1] == 0);
  bool vg2 = (cnts[cb+2] == 0), vg3 = (cnts[cb+3] == 0);

  const float4* bp = (const float4*)base + (long long)chunk * (K * D4);
  const float4* cp = (const float4*)cavg;

  float4 A0[3], A1[3], A2[3], A3[3];
#pragma unroll
  for (int t = 0; t < 3; ++t) {
    int o = t * 64 + l;
    A0[t] = vg0 ? cp[(k0+0)*D4 + o] : bp[(k0+0)*D4 + o];
    A1[t] = vg1 ? cp[(k0+1)*D4 + o] : bp[(k0+1)*D4 + o];
    A2[t] = vg2 ? cp[(k0+2)*D4 + o] : bp[(k0+2)*D4 + o];
    A3[t] = vg3 ? cp[(k0+3)*D4 + o] : bp[(k0+3)*D4 + o];
  }
  float n0 = 0.f, n1 = 0.f, n2 = 0.f, n3 = 0.f;
#pragma unroll
  for (int t = 0; t < 3; ++t) {
    n0 += d4f(A0[t], A0[t]); n1 += d4f(A1[t], A1[t]);
    n2 += d4f(A2[t], A2[t]); n3 += d4f(A3[t], A3[t]);
  }
#pragma unroll
  for (int m = 1; m <= 32; m <<= 1) {
    n0 += __shfl_xor(n0, m); n1 += __shfl_xor(n1, m);
    n2 += __shfl_xor(n2, m); n3 += __shfl_xor(n3, m);
  }

  const long long ibase = (long long)chunk * C;
  for (int j = 0; j < C; ++j) {
    const long long i = ibase + j;
    const int lab = labels[i];
    const float4* vp = (const float4*)inputs + i * D4;
    float4 v0 = vp[l], v1 = vp[64 + l], v2 = vp[128 + l];

    float p0 = d4f(A0[0], v0) + d4f(A0[1], v1) + d4f(A0[2], v2);
    float p1 = d4f(A1[0], v0) + d4f(A1[1], v1) + d4f(A1[2], v2);
    float p2 = d4f(A2[0], v0) + d4f(A2[1], v1) + d4f(A2[2], v2);
    float p3 = d4f(A3[0], v0) + d4f(A3[1], v1) + d4f(A3[2], v2);
    float pv = d4f(v0, v0) + d4f(v1, v1) + d4f(v2, v2);
#pragma unroll
    for (int m = 1; m <= 32; m <<= 1) {
      p0 += __shfl_xor(p0, m); p1 += __shfl_xor(p1, m);
      p2 += __shfl_xor(p2, m); p3 += __shfl_xor(p3, m);
      pv += __shfl_xor(pv, m);
    }
    if (l < 4) {
      float ps = (l == 0) ? p0 : (l == 1) ? p1 : (l == 2) ? p2 : p3;
      float ns = (l == 0) ? n0 : (l == 1) ? n1 : (l == 2) ? n2 : n3;
      out[i * K + k0 + l] = ps * rsqrtf(fmaxf(ns * pv, 1e-30f));
    }
#define UPD(idx) do { \
      if (vg##idx) { A##idx[0]=v0; A##idx[1]=v1; A##idx[2]=v2; n##idx = pv; vg##idx = false; } \
      else { A##idx[0]=a4(A##idx[0],v0); A##idx[1]=a4(A##idx[1],v1); A##idx[2]=a4(A##idx[2],v2); \
             n##idx += 2.f * p##idx + pv; } } while (0)
    if      (lab == k0 + 0) UPD(0);
    else if (lab == k0 + 1) UPD(1);
    else if (lab == k0 + 2) UPD(2);
    else if (lab == k0 + 3) UPD(3);
#undef UPD
  }
}

// =====================================================================
extern "C" void kernel_launch(void* const* d_in, const int* in_sizes, int n_in,
                              void* d_out, int out_size, void* d_ws, size_t ws_size,
                              hipStream_t stream)
{
  const float* inputs = (const float*)d_in[0];
  const int*   labels = (const int*)d_in[1];
  const float* cavg   = (const float*)d_in[2];
  float* out = (float*)d_out;
  const int N = in_sizes[1];

  const size_t szSums  = (size_t)NCF * K * D * 2;     // 25.2 MB (bf16, scanned in place)
  const size_t szAux   = (size_t)16 * K * D * 4;      // 3.1 MB
  const size_t szDot   = (size_t)NF * 128 * 4;        // 16.8 MB
  const size_t szPvb   = (size_t)NF * 4;              // 128 KB
  const size_t szBn2   = (size_t)NCF * K * 4;         // 64 KB
  const size_t szCnt   = (size_t)K * NCF * 4;
  const size_t szCavgb = (size_t)K * D * 2;
  const size_t szCn2   = (size_t)K * 4;
  size_t need = szSums + szAux + szDot + szPvb + szBn2 + szCnt + szCavgb + szCn2 + 10 * 256;

  if (N == NF && in_sizes[2] == K * D && ws_size >= need) {
    char* p = (char*)d_ws;
    auto take = [&](size_t b) { char* r = p; p += (b + 255) & ~(size_t)255; return r; };
    unsigned short* sums  = (unsigned short*)take(szSums);
    float*          aux   = (float*)take(szAux);
    float*          dotb  = (float*)take(szDot);
    float*          pvb   = (float*)take(szPvb);
    float*          bn2b  = (float*)take(szBn2);
    int*            cnts  = (int*)take(szCnt);
    unsigned short* cavgb = (unsigned short*)take(szCavgb);
    float*          cn2   = (float*)take(szCn2);

    hipLaunchKernelGGL(k2_v11, dim3(NCF * 12 + 16), dim3(256), 0, stream,
                       inputs, labels, cavg, cavgb, cn2, sums, cnts);
    hipLaunchKernelGGL(k3a_scan_lo, dim3(16 * 96), dim3(256), 0, stream, sums, aux);
    hipLaunchKernelGGL(k3b_plus, dim3(193), dim3(256), 0, stream, aux, cnts);
    hipLaunchKernelGGL(k4a_gemm, dim3(NCF * 2), dim3(512), 0, stream,
                       inputs, sums, aux, cavgb, labels, dotb, pvb, bn2b);
    hipLaunchKernelGGL(k5_ep, dim3(NCF), dim3(1024), 0, stream,
                       dotb, pvb, bn2b, labels, cnts, cn2, out);
    return;
  }

  // ---------------- fallback: round-1 pipeline ----------------
  int NC = 256;
  while (NC > 1) {
    size_t nd = (size_t)NC * K * D * 4 + (size_t)NC * K * 4;
    if (nd <= ws_size && (N % (NC * 4)) == 0) break;
    NC >>= 1;
  }
  const int C = N / NC;
  float* d_sums = (float*)d_ws;
  int*   d_cnts = (int*)((char*)d_ws + (size_t)NC * K * D * 4);

  hipLaunchKernelGGL(ph1_chunk_sums, dim3(NC * 12), dim3(256), 0, stream,
                     inputs, labels, d_sums, d_cnts, NC, C);
  hipLaunchKernelGGL(ph2a_scan_sums, dim3((K * D) / 256), dim3(256), 0, stream,
                     d_sums, NC);
  hipLaunchKernelGGL(ph2b_scan_cnts, dim3(1), dim3(64), 0, stream,
                     d_cnts, NC);
  hipLaunchKernelGGL(ph3_scan, dim3(NC * 4), dim3(256), 0, stream,
                     inputs, labels, cavg, d_sums, d_cnts, out, NC, C);
}

// Round 16
// 72.892 us; speedup vs baseline: 1.7187x; 1.7187x over previous
//
#include <hip/hip_runtime.h>
#include <cstddef>

#define K 64
#define D 768
#define D4 192   // D/4

__device__ __forceinline__ float d4f(float4 a, float4 b) {
  return a.x*b.x + a.y*b.y + a.z*b.z + a.w*b.w;
}
__device__ __forceinline__ float4 a4(float4 a, float4 b) {
  return make_float4(a.x+b.x, a.y+b.y, a.z+b.z, a.w+b.w);
}
__device__ __forceinline__ unsigned short f2bf(float x) {
  unsigned int u = __float_as_uint(x);
  unsigned int r = (u + 0x7FFFu + ((u >> 16) & 1u)) >> 16;
  return (unsigned short)r;
}
__device__ __forceinline__ float bflo(unsigned u) { return __uint_as_float(u << 16); }
__device__ __forceinline__ float bfhi(unsigned u) { return __uint_as_float(u & 0xFFFF0000u); }

typedef __attribute__((ext_vector_type(8)))  short bf16x8;
typedef __attribute__((ext_vector_type(16))) float f32x16;

// =====================================================================
// FAST PATH (N=32768, NC=256, C=128)
// =====================================================================
#define NCF 256
#define CF  128
#define NF  32768

// ---- K2v11: fused cast + per-chunk sums GEMM; 64-col slabs, 4 blocks/CU ----
#define LDT3 68   // Vt row stride (bf16 elems) for 64-col slab
#define LDM  136  // Mt row stride
__global__ __launch_bounds__(256) void k2_v11(
    const float* __restrict__ inputs, const int* __restrict__ labels,
    const float* __restrict__ cavg, unsigned short* __restrict__ cavgb,
    float* __restrict__ cn2,
    unsigned short* __restrict__ sums, int* __restrict__ cnts_t)
{
  __shared__ unsigned short Vt[128 * LDT3];   // 17408 B (reused as So)
  __shared__ unsigned short Mt[64 * LDM];     // 17408 B
  __shared__ int hist[64];
  const int bi = blockIdx.x;
  const int tid = threadIdx.x;

  if (bi >= NCF * 12) {   // ---- cavg tail: cast + exact row norms ----
    int wave = (bi - NCF * 12) * 4 + (tid >> 6);
    int l = tid & 63;
    if (wave >= K) return;
    const float* src = cavg + (size_t)wave * D;
    unsigned short* dst = cavgb + (size_t)wave * D;
    float sq = 0.f;
#pragma unroll
    for (int t = 0; t < 3; ++t) {
      float4 v = ((const float4*)src)[t * 64 + l];
      sq += v.x*v.x + v.y*v.y + v.z*v.z + v.w*v.w;
      ushort4 o; o.x = f2bf(v.x); o.y = f2bf(v.y); o.z = f2bf(v.z); o.w = f2bf(v.w);
      ((ushort4*)dst)[t * 64 + l] = o;
    }
#pragma unroll
    for (int mm = 1; mm <= 32; mm <<= 1) sq += __shfl_xor(sq, mm);
    if (l == 0) cn2[wave] = sq;
    return;
  }

  const int m = bi / 12, g = bi % 12;
  const int w = tid >> 6, l = tid & 63;
  const int r31 = l & 31, kh = l >> 5;
  const int ch = w & 1;    // class-half (rows of output)
  const int cw = w >> 1;   // col-half (32-col tile within 64-col slab)

  // issue f32 slab loads first; latency hides under Mt build
  float4 fr[8];
#pragma unroll
  for (int it = 0; it < 8; ++it) {
    int flat = it * 256 + tid;
    int row = flat >> 4, c4 = flat & 15;
    fr[it] = *(const float4*)(inputs + (size_t)(m * 128 + row) * D + g * 64 + c4 * 4);
  }

  for (int e = tid; e < 64 * LDM / 2; e += 256) ((unsigned int*)Mt)[e] = 0u;
  if (tid < 64) hist[tid] = 0;
  __syncthreads();
  if (tid < 128) {
    int lab = labels[m * 128 + tid];
    Mt[lab * LDM + tid] = 0x3F80;   // 1.0 bf16
    if (g == 0) atomicAdd(&hist[lab], 1);
  }
  __syncthreads();
  if (g == 0 && tid < 64) cnts_t[tid * NCF + m] = hist[tid];

  // convert + write Vt (LDS only)
#pragma unroll
  for (int it = 0; it < 8; ++it) {
    int flat = it * 256 + tid;
    int row = flat >> 4, c4 = flat & 15;
    ushort4 o;
    o.x = f2bf(fr[it].x); o.y = f2bf(fr[it].y);
    o.z = f2bf(fr[it].z); o.w = f2bf(fr[it].w);
    *(ushort4*)(Vt + row * LDT3 + c4 * 4) = o;
  }
  __syncthreads();

  f32x16 acc = (f32x16){};
#pragma unroll
  for (int kk = 0; kk < 8; ++kk) {
    bf16x8 a = *(const bf16x8*)(Mt + (ch * 32 + r31) * LDM + kk * 16 + kh * 8);
    bf16x8 b;
#pragma unroll
    for (int r = 0; r < 8; ++r)
      b[r] = *(const short*)(Vt + (kk * 16 + kh * 8 + r) * LDT3 + cw * 32 + r31);
    acc = __builtin_amdgcn_mfma_f32_32x32x16_bf16(a, b, acc, 0, 0, 0);
  }

  // coalesced output: acc -> LDS (reuse Vt) -> row-contiguous global stores
  __syncthreads();
  unsigned short* So = Vt;   // [64][64]
#pragma unroll
  for (int q = 0; q < 16; ++q) {
    int kc = (q & 3) + 8 * (q >> 2) + 4 * kh;
    So[(ch * 32 + kc) * 64 + cw * 32 + r31] = f2bf(acc[q]);
  }
  __syncthreads();
  unsigned short* sp = sums + (size_t)m * (K * D) + g * 64;
#pragma unroll
  for (int it = 0; it < 2; ++it) {
    int flat = it * 256 + tid;
    int row = flat >> 3, c = flat & 7;
    *(uint4*)(sp + (size_t)row * D + c * 8) = *(const uint4*)(So + row * 64 + c * 8);
  }
}

// ---- K3a: level-1 exclusive scan over 16 chunks, IN PLACE on bf16 sums ----
__global__ __launch_bounds__(256) void k3a_scan_lo(
    unsigned short* __restrict__ sums, float* __restrict__ aux)
{
  const int g  = blockIdx.x / 96;
  const int cp = (blockIdx.x % 96) * 256 + threadIdx.x;  // column pair
  const int col = cp * 2;
  float run0 = 0.f, run1 = 0.f;
  for (int m = g * 16; m < g * 16 + 16; ++m) {
    size_t idx = (size_t)m * (K * D) + col;
    unsigned u = *(const unsigned*)(sums + idx);
    float t0 = bflo(u), t1 = bfhi(u);
    *(unsigned*)(sums + idx) = (unsigned)f2bf(run0) | ((unsigned)f2bf(run1) << 16);
    run0 += t0; run1 += t1;
  }
  aux[(size_t)g * (K * D) + col]     = run0;
  aux[(size_t)g * (K * D) + col + 1] = run1;
}

// ---- K3b+: scan group totals (f32); block 192 scans cnts ----
__global__ __launch_bounds__(256) void k3b_plus(
    float* __restrict__ aux, int* __restrict__ cnts_t)
{
  if (blockIdx.x == 192) {
    if (threadIdx.x < K) {
      int k = threadIdx.x;
      int run = 0;
      int* p = cnts_t + k * NCF;
      for (int mm = 0; mm < NCF; ++mm) { int t = p[mm]; p[mm] = run; run += t; }
    }
    return;
  }
  int col = blockIdx.x * 256 + threadIdx.x;
  float run = 0.f;
  for (int g = 0; g < 16; ++g) {
    size_t idx = (size_t)g * (K * D) + col;
    float t = aux[idx]; aux[idx] = run; run += t;
  }
}

// ---- K4v8: fused GEMMs + epilogue; V from f32 inputs; parallel seg-scan ----
#define LDV2 136  // bf16 row stride for 128-col tiles
#define LDD  132  // f32 dot LDS stride
#define BUFW (2 * 128 * LDV2)   // one buffer = Vt|Bt
__global__ __launch_bounds__(1024, 4) void k4_v8(
    const float* __restrict__ inputs, const unsigned short* __restrict__ base,
    const float* __restrict__ aux, const unsigned short* __restrict__ cavgb,
    const int* __restrict__ labels, const int* __restrict__ cnts_t,
    const float* __restrict__ cn2, float* __restrict__ out)
{
  __shared__ unsigned short smem[2 * BUFW];   // 139264 B
  __shared__ float pvL[128];
  __shared__ float bn2L[64];
  __shared__ int   labL[128];
  __shared__ float segA[16][64];
  __shared__ float segF[16][64];
  __shared__ float segP[16][64];
  __shared__ int   segH[16][64];
  const int m = blockIdx.x;
  const int g = m >> 4;
  const int tid = threadIdx.x;
  const int w = tid >> 6, l = tid & 63;
  const int r31 = l & 31, kh = l >> 5;
  const int wr = w & 3;    // output row-tile (32 rows)
  const int wc = w >> 2;   // output col-tile (32 cols)

  if (tid < 128) labL[tid] = labels[m * 128 + tid];
  if (tid < 64) bn2L[tid] = 0.f;
  __syncthreads();

  f32x16 accP = (f32x16){}, accS = (f32x16){};

  float4 vregf[4];       // V slab as f32: 4x (row, 4-col granule)
  uint4 breg, creg;
  float4 areg[2];

#define PREF(sx) do {                                                          \
    _Pragma("unroll")                                                          \
    for (int it = 0; it < 4; ++it) {                                           \
      int flat = it * 1024 + tid;                                              \
      int row = flat >> 5, c4 = flat & 31;                                     \
      vregf[it] = *(const float4*)(inputs + (size_t)(m * 128 + row) * D + (sx) * 128 + c4 * 4); \
    }                                                                          \
    _Pragma("unroll")                                                          \
    for (int it = 0; it < 2; ++it) {                                           \
      int flat = it * 1024 + tid;                                              \
      int row = flat >> 4, c = flat & 15;                                      \
      if (it == 0) {                                                           \
        breg = *(const uint4*)(base + ((size_t)m * K + row) * D + (sx) * 128 + c * 8); \
        const float* ap = aux + ((size_t)g * K + row) * D + (sx) * 128 + c * 8; \
        areg[0] = *(const float4*)ap;                                          \
        areg[1] = *(const float4*)(ap + 4);                                    \
      } else {                                                                 \
        creg = *(const uint4*)(cavgb + (size_t)(row - 64) * D + (sx) * 128 + c * 8); \
      }                                                                        \
    }                                                                          \
  } while (0)

#define WRITEB(pb) do {                                                        \
    unsigned short* Vt_ = smem + (pb) * BUFW;                                  \
    unsigned short* Bt_ = Vt_ + 128 * LDV2;                                    \
    _Pragma("unroll")                                                          \
    for (int it = 0; it < 4; ++it) {                                           \
      int flat = it * 1024 + tid;                                              \
      int row = flat >> 5, c4 = flat & 31;                                     \
      ushort4 o;                                                               \
      o.x = f2bf(vregf[it].x); o.y = f2bf(vregf[it].y);                        \
      o.z = f2bf(vregf[it].z); o.w = f2bf(vregf[it].w);                        \
      *(ushort4*)(Vt_ + row * LDV2 + c4 * 4) = o;                              \
    }                                                                          \
    _Pragma("unroll")                                                          \
    for (int it = 0; it < 2; ++it) {                                           \
      int flat = it * 1024 + tid;                                              \
      int row = flat >> 4, c = flat & 15;                                      \
      if (it == 0) {                                                           \
        uint4 ub = breg;                                                       \
        float4 af0 = areg[0], af1 = areg[1];                                   \
        float f0 = bflo(ub.x) + af0.x, f1 = bfhi(ub.x) + af0.y;                \
        float f2 = bflo(ub.y) + af0.z, f3 = bfhi(ub.y) + af0.w;                \
        float f4 = bflo(ub.z) + af1.x, f5 = bfhi(ub.z) + af1.y;                \
        float f6 = bflo(ub.w) + af1.z, f7 = bfhi(ub.w) + af1.w;                \
        float sq = f0*f0 + f1*f1 + f2*f2 + f3*f3 + f4*f4 + f5*f5 + f6*f6 + f7*f7; \
        sq += __shfl_xor(sq, 1); sq += __shfl_xor(sq, 2);                      \
        sq += __shfl_xor(sq, 4); sq += __shfl_xor(sq, 8);                      \
        if ((l & 15) == 0) atomicAdd(&bn2L[row], sq);                          \
        uint4 u;                                                               \
        u.x = (unsigned)f2bf(f0) | ((unsigned)f2bf(f1) << 16);                 \
        u.y = (unsigned)f2bf(f2) | ((unsigned)f2bf(f3) << 16);                 \
        u.z = (unsigned)f2bf(f4) | ((unsigned)f2bf(f5) << 16);                 \
        u.w = (unsigned)f2bf(f6) | ((unsigned)f2bf(f7) << 16);                 \
        *(uint4*)(Bt_ + row * LDV2 + c * 8) = u;                               \
      } else {                                                                 \
        *(uint4*)(Bt_ + row * LDV2 + c * 8) = creg;                            \
      }                                                                        \
    }                                                                          \
  } while (0)

  PREF(0);
  WRITEB(0);
  PREF(1);
  __syncthreads();

  for (int s = 0; s < 6; ++s) {
    const int pb = s & 1;
    if (s < 5) WRITEB(pb ^ 1);     // write next slab (buffer free since barrier)
    if (s < 4) PREF(s + 2);        // refill regs; lands under MFMAs
    const unsigned short* Vt = smem + pb * BUFW;
    const unsigned short* Bt = Vt + 128 * LDV2;
#pragma unroll
    for (int kk = 0; kk < 8; ++kk) {
      bf16x8 av = *(const bf16x8*)(Vt + (32 * wr + r31) * LDV2 + kk * 16 + kh * 8);
      bf16x8 bB = *(const bf16x8*)(Bt + (32 * wc + r31) * LDV2 + kk * 16 + kh * 8);
      accP = __builtin_amdgcn_mfma_f32_32x32x16_bf16(av, bB, accP, 0, 0, 0);
      if (wc <= wr) {   // strict-lower + diag tiles only (upper fully masked)
        bf16x8 bV = *(const bf16x8*)(Vt + (32 * wc + r31) * LDV2 + kk * 16 + kh * 8);
        accS = __builtin_amdgcn_mfma_f32_32x32x16_bf16(av, bV, accS, 0, 0, 0);
      }
    }
    __syncthreads();
  }
#undef PREF
#undef WRITEB

  // ---- pv from Gram diagonal (diag tiles: wr==wc) ----
  if (wr == wc && ((r31 >> 2) & 1) == kh) {
    int q = (r31 & 3) + 4 * (r31 >> 3);
    pvL[32 * wr + r31] = accS[q];
  }

  // ---- masked S -> bf16 into buf0.Vt; one-hot Mt into buf0.Bt ----
  {
    unsigned short* Vt = smem;
    unsigned short* Bt = smem + 128 * LDV2;
#pragma unroll
    for (int q = 0; q < 16; ++q) {
      int i = 32 * wr + (q & 3) + 8 * (q >> 2) + 4 * kh;
      int j = 32 * wc + r31;
      Vt[i * LDV2 + j] = (j < i) ? f2bf(accS[q]) : (unsigned short)0;
    }
    int j = tid & 127;
    int lab = labL[j];
    int kb = (tid >> 7) * 8;
#pragma unroll
    for (int kk = 0; kk < 8; ++kk) {
      int k = kb + kk;
      Bt[k * LDV2 + j] = (lab == k) ? (unsigned short)0x3F80 : (unsigned short)0;
    }
  }
  __syncthreads();

  // ---- corr = tril_strict(S) @ onehot; waves 0-7 own the class-col tiles ----
  if (w < 8) {
    const unsigned short* Vt = smem;
    const unsigned short* Bt = smem + 128 * LDV2;
#pragma unroll
    for (int kk = 0; kk < 8; ++kk) {
      bf16x8 aS = *(const bf16x8*)(Vt + (32 * wr + r31) * LDV2 + kk * 16 + kh * 8);
      bf16x8 bM = *(const bf16x8*)(Bt + (32 * wc + r31) * LDV2 + kk * 16 + kh * 8);
      accP = __builtin_amdgcn_mfma_f32_32x32x16_bf16(aS, bM, accP, 0, 0, 0);
    }
  }
  __syncthreads();

  // ---- dot matrix -> LDS ----
  float* dotL = (float*)smem;
#pragma unroll
  for (int q = 0; q < 16; ++q) {
    int i = 32 * wr + (q & 3) + 8 * (q >> 2) + 4 * kh;
    dotL[i * LDD + 32 * wc + r31] = accP[q];
  }
  __syncthreads();

  // ---- parallel segment summaries: wave w owns rows [8w, 8w+8), lane = class ----
  {
    int k = l;
    float A = 0.f, Fv = 0.f, Pv = 0.f;
    int has = 0;
    int jb = w * 8;
    for (int j = jb; j < jb + 8; ++j) {
      if (labL[j] == k) {
        float t = 2.f * dotL[j * LDD + k] + pvL[j];
        A += t;
        if (!has) { Fv = t; Pv = pvL[j]; has = 1; }
      }
    }
    segA[w][k] = A; segF[w][k] = Fv; segP[w][k] = Pv; segH[w][k] = has;
  }
  __syncthreads();

  // ---- fold prior segments, then emit 8-row segment ----
  {
    int k = l;
    bool seen = cnts_t[k * NCF + m] > 0;
    float n = seen ? bn2L[k] : 0.f;
    for (int ww = 0; ww < w; ++ww) {
      if (segH[ww][k]) {
        n = seen ? (n + segA[ww][k])
                 : (segP[ww][k] + segA[ww][k] - segF[ww][k]);
        seen = true;
      }
    }
    float cnk = cn2[k];
    int jb = w * 8;
    for (int j = jb; j < jb + 8; ++j) {
      float dS = dotL[j * LDD + k];
      float dC = dotL[j * LDD + 64 + k];
      float pvj = pvL[j];
      int lab = labL[j];
      float val = seen ? dS : dC;
      float nn  = seen ? n : cnk;
      out[(size_t)(m * 128 + j) * K + k] = val * rsqrtf(fmaxf(nn * pvj, 1e-30f));
      if (lab == k) {
        n = seen ? (n + 2.f * dS + pvj) : pvj;
        seen = true;
      }
    }
  }
}

// =====================================================================
// FALLBACK PATH — round-1 pipeline, verbatim (known-correct)
// =====================================================================
__global__ __launch_bounds__(256) void ph1_chunk_sums(
    const float* __restrict__ inputs, const int* __restrict__ labels,
    float* __restrict__ sums, int* __restrict__ cnts, int NC, int C)
{
  __shared__ float acc[4 * K * 64];
  __shared__ int   hist[4 * K];
  const int bi    = blockIdx.x;
  const int chunk = bi / 12, slice = bi % 12;
  const int w = threadIdx.x >> 6, l = threadIdx.x & 63;

  for (int e = threadIdx.x; e < 4 * K * 64; e += 256) acc[e] = 0.f;
  hist[threadIdx.x] = 0;
  __syncthreads();

  const int C4 = C >> 2;
  const long long rbase = (long long)chunk * C + (long long)w * C4;
  float* accw = acc + w * (K * 64);
  for (int j = 0; j < C4; ++j) {
    long long r = rbase + j;
    int lab = labels[r];
    float v = inputs[r * D + slice * 64 + l];
    accw[lab * 64 + l] += v;
    if (slice == 0 && l == 0) hist[w * K + lab]++;
  }
  __syncthreads();

  float* sp = sums + (long long)chunk * (K * D) + slice * 64;
  for (int e = threadIdx.x; e < K * 64; e += 256) {
    int k = e >> 6, dl = e & 63;
    float s = acc[0*K*64 + e] + acc[1*K*64 + e] + acc[2*K*64 + e] + acc[3*K*64 + e];
    sp[k * D + dl] = s;
  }
  if (slice == 0 && threadIdx.x < K) {
    cnts[chunk * K + threadIdx.x] =
        hist[0*K + threadIdx.x] + hist[1*K + threadIdx.x] +
        hist[2*K + threadIdx.x] + hist[3*K + threadIdx.x];
  }
}

__global__ __launch_bounds__(256) void ph2a_scan_sums(float* __restrict__ sums, int NC)
{
  const int tid = blockIdx.x * 256 + threadIdx.x;
  float run = 0.f;
  for (int m = 0; m < NC; ++m) {
    long long idx = (long long)m * (K * D) + tid;
    float t = sums[idx];
    sums[idx] = run;
    run += t;
  }
}

__global__ void ph2b_scan_cnts(int* __restrict__ cnts, int NC)
{
  const int k = threadIdx.x;
  int run = 0;
  for (int m = 0; m < NC; ++m) {
    int t = cnts[m * K + k];
    cnts[m * K + k] = run;
    run += t;
  }
}

__global__ __launch_bounds__(256, 4) void ph3_scan(
    const float* __restrict__ inputs, const int* __restrict__ labels,
    const float* __restrict__ cavg, const float* __restrict__ base,
    const int* __restrict__ cnts, float* __restrict__ out, int NC, int C)
{
  const int bi = blockIdx.x;
  int chunk, quad;
  if (NC >= 8) {
    int xcd = bi & 7, slot = bi >> 3;
    chunk = xcd * (NC >> 3) + (slot >> 2);
    quad  = slot & 3;
  } else {
    chunk = bi >> 2; quad = bi & 3;
  }
  const int w = threadIdx.x >> 6, l = threadIdx.x & 63;
  const int k0 = (quad * 4 + w) * 4;

  const int cb = chunk * K + k0;
  bool vg0 = (cnts[cb+0] == 0), vg1 = (cnts[cb+1] == 0);
  bool vg2 = (cnts[cb+2] == 0), vg3 = (cnts[cb+3] == 0);

  const float4* bp = (const float4*)base + (long long)chunk * (K * D4);
  const float4* cp = (const float4*)cavg;

  float4 A0[3], A1[3], A2[3], A3[3];
#pragma unroll
  for (int t = 0; t < 3; ++t) {
    int o = t * 64 + l;
    A0[t] = vg0 ? cp[(k0+0)*D4 + o] : bp[(k0+0)*D4 + o];
    A1[t] = vg1 ? cp[(k0+1)*D4 + o] : bp[(k0+1)*D4 + o];
    A2[t] = vg2 ? cp[(k0+2)*D4 + o] : bp[(k0+2)*D4 + o];
    A3[t] = vg3 ? cp[(k0+3)*D4 + o] : bp[(k0+3)*D4 + o];
  }
  float n0 = 0.f, n1 = 0.f, n2 = 0.f, n3 = 0.f;
#pragma unroll
  for (int t = 0; t < 3; ++t) {
    n0 += d4f(A0[t], A0[t]); n1 += d4f(A1[t], A1[t]);
    n2 += d4f(A2[t], A2[t]); n3 += d4f(A3[t], A3[t]);
  }
#pragma unroll
  for (int m = 1; m <= 32; m <<= 1) {
    n0 += __shfl_xor(n0, m); n1 += __shfl_xor(n1, m);
    n2 += __shfl_xor(n2, m); n3 += __shfl_xor(n3, m);
  }

  const long long ibase = (long long)chunk * C;
  for (int j = 0; j < C; ++j) {
    const long long i = ibase + j;
    const int lab = labels[i];
    const float4* vp = (const float4*)inputs + i * D4;
    float4 v0 = vp[l], v1 = vp[64 + l], v2 = vp[128 + l];

    float p0 = d4f(A0[0], v0) + d4f(A0[1], v1) + d4f(A0[2], v2);
    float p1 = d4f(A1[0], v0) + d4f(A1[1], v1) + d4f(A1[2], v2);
    float p2 = d4f(A2[0], v0) + d4f(A2[1], v1) + d4f(A2[2], v2);
    float p3 = d4f(A3[0], v0) + d4f(A3[1], v1) + d4f(A3[2], v2);
    float pv = d4f(v0, v0) + d4f(v1, v1) + d4f(v2, v2);
#pragma unroll
    for (int m = 1; m <= 32; m <<= 1) {
      p0 += __shfl_xor(p0, m); p1 += __shfl_xor(p1, m);
      p2 += __shfl_xor(p2, m); p3 += __shfl_xor(p3, m);
      pv += __shfl_xor(pv, m);
    }
    if (l < 4) {
      float ps = (l == 0) ? p0 : (l == 1) ? p1 : (l == 2) ? p2 : p3;
      float ns = (l == 0) ? n0 : (l == 1) ? n1 : (l == 2) ? n2 : n3;
      out[i * K + k0 + l] = ps * rsqrtf(fmaxf(ns * pv, 1e-30f));
    }
#define UPD(idx) do { \
      if (vg##idx) { A##idx[0]=v0; A##idx[1]=v1; A##idx[2]=v2; n##idx = pv; vg##idx = false; } \
      else { A##idx[0]=a4(A##idx[0],v0); A##idx[1]=a4(A##idx[1],v1); A##idx[2]=a4(A##idx[2],v2); \
             n##idx += 2.f * p##idx + pv; } } while (0)
    if      (lab == k0 + 0) UPD(0);
    else if (lab == k0 + 1) UPD(1);
    else if (lab == k0 + 2) UPD(2);
    else if (lab == k0 + 3) UPD(3);
#undef UPD
  }
}

// =====================================================================
extern "C" void kernel_launch(void* const* d_in, const int* in_sizes, int n_in,
                              void* d_out, int out_size, void* d_ws, size_t ws_size,
                              hipStream_t stream)
{
  const float* inputs = (const float*)d_in[0];
  const int*   labels = (const int*)d_in[1];
  const float* cavg   = (const float*)d_in[2];
  float* out = (float*)d_out;
  const int N = in_sizes[1];

  const size_t szSums  = (size_t)NCF * K * D * 2; // 25.2 MB (bf16, scanned in place)
  const size_t szAux   = (size_t)16 * K * D * 4;  // 3.1 MB
  const size_t szCnt   = (size_t)K * NCF * 4;
  const size_t szCavgb = (size_t)K * D * 2;
  const size_t szCn2   = (size_t)K * 4;
  size_t need = szSums + szAux + szCnt + szCavgb + szCn2 + 8 * 256;

  if (N == NF && in_sizes[2] == K * D && ws_size >= need) {
    char* p = (char*)d_ws;
    auto take = [&](size_t b) { char* r = p; p += (b + 255) & ~(size_t)255; return r; };
    unsigned short* sums  = (unsigned short*)take(szSums);
    float*          aux   = (float*)take(szAux);
    int*            cnts  = (int*)take(szCnt);
    unsigned short* cavgb = (unsigned short*)take(szCavgb);
    float*          cn2   = (float*)take(szCn2);

    hipLaunchKernelGGL(k2_v11, dim3(NCF * 12 + 16), dim3(256), 0, stream,
                       inputs, labels, cavg, cavgb, cn2, sums, cnts);
    hipLaunchKernelGGL(k3a_scan_lo, dim3(16 * 96), dim3(256), 0, stream, sums, aux);
    hipLaunchKernelGGL(k3b_plus, dim3(193), dim3(256), 0, stream, aux, cnts);
    hipLaunchKernelGGL(k4_v8, dim3(NCF), dim3(1024), 0, stream,
                       inputs, sums, aux, cavgb, labels, cnts, cn2, out);
    return;
  }

  // ---------------- fallback: round-1 pipeline ----------------
  int NC = 256;
  while (NC > 1) {
    size_t nd = (size_t)NC * K * D * 4 + (size_t)NC * K * 4;
    if (nd <= ws_size && (N % (NC * 4)) == 0) break;
    NC >>= 1;
  }
  const int C = N / NC;
  float* d_sums = (float*)d_ws;
  int*   d_cnts = (int*)((char*)d_ws + (size_t)NC * K * D * 4);

  hipLaunchKernelGGL(ph1_chunk_sums, dim3(NC * 12), dim3(256), 0, stream,
                     inputs, labels, d_sums, d_cnts, NC, C);
  hipLaunchKernelGGL(ph2a_scan_sums, dim3((K * D) / 256), dim3(256), 0, stream,
                     d_sums, NC);
  hipLaunchKernelGGL(ph2b_scan_cnts, dim3(1), dim3(64), 0, stream,
                     d_cnts, NC);
  hipLaunchKernelGGL(ph3_scan, dim3(NC * 4), dim3(256), 0, stream,
                     inputs, labels, cavg, d_sums, d_cnts, out, NC, C);
}